// Round 3
// baseline (546.088 us; speedup 1.0000x reference)
//
#include <hip/hip_runtime.h>

#define DEV __device__ __forceinline__

// ---------- vector types (own ext_vector types; may_alias versions for reinterpret access) ----------
typedef float          f32x4  __attribute__((ext_vector_type(4)));
typedef unsigned int   u32x4  __attribute__((ext_vector_type(4)));
typedef unsigned short u16x4  __attribute__((ext_vector_type(4)));
typedef __bf16         vbf8   __attribute__((ext_vector_type(8)));
typedef short          vs8    __attribute__((ext_vector_type(8)));

typedef f32x4 f32x4_a __attribute__((may_alias));
typedef u32x4 u32x4_a __attribute__((may_alias));
typedef u16x4 u16x4_a __attribute__((may_alias));

// ---------- bf16 helpers (RNE) ----------
DEV unsigned short f2bf(float f) {
  unsigned int u = __float_as_uint(f);
  u += 0x7fffu + ((u >> 16) & 1u);
  return (unsigned short)(u >> 16);
}

// ---------- MFMA shim: works whether the gfx950 builtin takes v8bf16 or v8i16 ----------
struct MfmaNope {};
template <class T, class U> struct SameT { static constexpr bool value = false; };
template <class T> struct SameT<T, T> { static constexpr bool value = true; };

template <typename A>
DEV auto mfma_try(A a, A b, f32x4 c, int)
    -> decltype(__builtin_amdgcn_mfma_f32_16x16x32_bf16(a, b, c, 0, 0, 0)) {
  return __builtin_amdgcn_mfma_f32_16x16x32_bf16(a, b, c, 0, 0, 0);
}
template <typename A>
DEV MfmaNope mfma_try(A, A, f32x4, long) { return MfmaNope{}; }

template <typename I4 = u32x4>
DEV f32x4 mfma_bf16(I4 a, I4 b, f32x4 c) {
  auto r = mfma_try(__builtin_bit_cast(vbf8, a), __builtin_bit_cast(vbf8, b), c, 0);
  if constexpr (SameT<decltype(r), MfmaNope>::value) {
    return mfma_try(__builtin_bit_cast(vs8, a), __builtin_bit_cast(vs8, b), c, 0);
  } else {
    return r;
  }
}

// Fragment layout used throughout (16x16x32 bf16):
//   A[m][k]: m = lane&15, k = (lane>>4)*8 + j  (8 contiguous bf16 -> one b128)
//   B[k][n]: n = lane&15, k = (lane>>4)*8 + j
//   C[m][n]: n = lane&15, m = (lane>>4)*4 + reg

// =====================================================================
// Kernel 1: LayerNorm fp32 -> bf16   (8192 rows of 1024)
// =====================================================================
__global__ __launch_bounds__(256) void k_ln(const float* __restrict__ x,
                                            unsigned short* __restrict__ xn) {
  const int row = blockIdx.x;
  const int t = threadIdx.x;
  f32x4 v = *reinterpret_cast<const f32x4_a*>(x + (size_t)row * 1024 + t * 4);
  float s = v[0] + v[1] + v[2] + v[3];
  float q = v[0]*v[0] + v[1]*v[1] + v[2]*v[2] + v[3]*v[3];
#pragma unroll
  for (int o = 32; o > 0; o >>= 1) { s += __shfl_xor(s, o); q += __shfl_xor(q, o); }
  __shared__ float rs_[4], rq_[4];
  const int w = t >> 6;
  if ((t & 63) == 0) { rs_[w] = s; rq_[w] = q; }
  __syncthreads();
  s = rs_[0] + rs_[1] + rs_[2] + rs_[3];
  q = rq_[0] + rq_[1] + rq_[2] + rq_[3];
  const float mu = s * (1.0f / 1024.0f);
  const float rstd = rsqrtf(q * (1.0f / 1024.0f) - mu * mu + 1e-5f);
  u16x4 o;
#pragma unroll
  for (int i = 0; i < 4; ++i) o[i] = f2bf((v[i] - mu) * rstd);
  *reinterpret_cast<u16x4_a*>(xn + (size_t)row * 1024 + t * 4) = o;
}

// =====================================================================
// Kernel 2a: repack Wq/Wk/Wv [16][1024][64] fp32 -> Wt rows [3072][1024] bf16
//   row n = sel*1024 + h*64 + k holds W_sel[h][:,k]  (B^T layout for GEMM)
// grid (16 d-chunks, 48 = sel*16+h)
// =====================================================================
__global__ __launch_bounds__(256) void k_repw(const float* __restrict__ Wq,
                                              const float* __restrict__ Wk,
                                              const float* __restrict__ Wv,
                                              unsigned short* __restrict__ Wt) {
  __shared__ float ld[64][65];
  const int d0 = blockIdx.x * 64;
  const int sh = blockIdx.y;
  const int sel = sh >> 4, h = sh & 15;
  const float* W = (sel == 0) ? Wq : (sel == 1) ? Wk : Wv;
  const float* src = W + (size_t)h * 1024 * 64;
  const int t = threadIdx.x;
#pragma unroll
  for (int r = 0; r < 16; ++r) {
    const int e = t + 256 * r;
    const int dl = e >> 6, k = e & 63;
    ld[dl][k] = src[(size_t)(d0 + dl) * 64 + k];
  }
  __syncthreads();
#pragma unroll
  for (int r = 0; r < 16; ++r) {
    const int e = t + 256 * r;
    const int k = e >> 6, dl = e & 63;
    Wt[(size_t)(sel * 1024 + h * 64 + k) * 1024 + d0 + dl] = f2bf(ld[dl][k]);
  }
}

// Kernel 2b: cast Wo [1024][1024] fp32 -> bf16 (already B^T layout for X @ Wo^T)
__global__ __launch_bounds__(256) void k_repo(const float* __restrict__ Wo,
                                              unsigned short* __restrict__ WoT) {
  const int j = blockIdx.x, t = threadIdx.x;
  f32x4 v = *reinterpret_cast<const f32x4_a*>(Wo + (size_t)j * 1024 + t * 4);
  u16x4 o;
#pragma unroll
  for (int i = 0; i < 4; ++i) o[i] = f2bf(v[i]);
  *reinterpret_cast<u16x4_a*>(WoT + (size_t)j * 1024 + t * 4) = o;
}

// =====================================================================
// Kernel 3: QKV GEMM.  A = xn [8192][1024] bf16, Bt = Wt [3072][1024] bf16.
// 128x128 tile, BK=64, 4 waves in 2x2, each 64x64. Output scattered to
// Q/K/V [b][h][s][64] bf16 with bias add. grid (24, 64).
// =====================================================================
__global__ __launch_bounds__(256) void k_qkv(const unsigned short* __restrict__ A,
                                             const unsigned short* __restrict__ Bt,
                                             const float* __restrict__ bq,
                                             const float* __restrict__ bk,
                                             const float* __restrict__ bv,
                                             unsigned short* __restrict__ Qo,
                                             unsigned short* __restrict__ Ko,
                                             unsigned short* __restrict__ Vo) {
  __shared__ __align__(16) unsigned short As[128][72];
  __shared__ __align__(16) unsigned short Bs[128][72];
  const int bn = blockIdx.x, bm = blockIdx.y;
  const int t = threadIdx.x;
  const int w = t >> 6, lane = t & 63, l15 = lane & 15, g = lane >> 4;
  const int wm = w & 1, wn = w >> 1;
  f32x4 acc[4][4] = {};
  const int am0 = bm * 128, bn0 = bn * 128;
  for (int kt = 0; kt < 16; ++kt) {
    const int k0 = kt * 64;
    __syncthreads();
#pragma unroll
    for (int r = 0; r < 4; ++r) {
      const int ci = t + 256 * r;
      const int row = ci >> 3, c8 = (ci & 7) * 8;
      *reinterpret_cast<u32x4_a*>(&As[row][c8]) =
          *reinterpret_cast<const u32x4_a*>(A + (size_t)(am0 + row) * 1024 + k0 + c8);
      *reinterpret_cast<u32x4_a*>(&Bs[row][c8]) =
          *reinterpret_cast<const u32x4_a*>(Bt + (size_t)(bn0 + row) * 1024 + k0 + c8);
    }
    __syncthreads();
#pragma unroll
    for (int kf = 0; kf < 2; ++kf) {
      u32x4 af[4], bf[4];
#pragma unroll
      for (int i = 0; i < 4; ++i)
        af[i] = *reinterpret_cast<const u32x4_a*>(&As[wm * 64 + i * 16 + l15][kf * 32 + g * 8]);
#pragma unroll
      for (int j = 0; j < 4; ++j)
        bf[j] = *reinterpret_cast<const u32x4_a*>(&Bs[wn * 64 + j * 16 + l15][kf * 32 + g * 8]);
#pragma unroll
      for (int i = 0; i < 4; ++i)
#pragma unroll
        for (int j = 0; j < 4; ++j)
          acc[i][j] = mfma_bf16(af[i], bf[j], acc[i][j]);
    }
  }
  const int sel = bn0 >> 10;
  const float* bias = (sel == 0) ? bq : (sel == 1) ? bk : bv;
  unsigned short* Out = (sel == 0) ? Qo : (sel == 1) ? Ko : Vo;
#pragma unroll
  for (int j = 0; j < 4; ++j) {
    const int n10 = (bn0 + wn * 64 + j * 16 + l15) & 1023;
    const float bval = bias[n10];
    const int h = n10 >> 6, kk = n10 & 63;
#pragma unroll
    for (int i = 0; i < 4; ++i) {
#pragma unroll
      for (int r = 0; r < 4; ++r) {
        const int m = am0 + wm * 64 + i * 16 + g * 4 + r;
        const int bidx = m >> 11, s = m & 2047;
        Out[((size_t)(bidx * 16 + h) * 2048 + s) * 64 + kk] = f2bf(acc[i][j][r] + bval);
      }
    }
  }
}

// =====================================================================
// Kernel 4: column softmax stats. For each (b,h) and key s:
//   m[s] = max_q (Q[q].K[s]/8),  l[s] = sum_q exp(.-m[s]).  Store m and 1/l.
// Block: (sblk of 128 s, bh). Loop over all 2048 q in tiles of 128.
// grid (16, 64).
// =====================================================================
__global__ __launch_bounds__(256) void k_stats(const unsigned short* __restrict__ Q,
                                               const unsigned short* __restrict__ K,
                                               float* __restrict__ mG,
                                               float* __restrict__ invlG) {
  __shared__ __align__(16) unsigned short Ks[128][72];
  __shared__ __align__(16) unsigned short Qs[128][72];
  __shared__ float redM[4][128], redL[4][128];
  const int sblk = blockIdx.x, bh = blockIdx.y;
  const unsigned short* Qh = Q + (size_t)bh * 2048 * 64;
  const unsigned short* Kh = K + (size_t)bh * 2048 * 64;
  const int t = threadIdx.x;
  const int w = t >> 6, lane = t & 63, l15 = lane & 15, g = lane >> 4;
  const float scale = 0.125f;  // 1/sqrt(64)

#pragma unroll
  for (int r = 0; r < 4; ++r) {
    const int ci = t + 256 * r;
    const int row = ci >> 3, c8 = (ci & 7) * 8;
    *reinterpret_cast<u32x4_a*>(&Ks[row][c8]) =
        *reinterpret_cast<const u32x4_a*>(Kh + ((size_t)sblk * 128 + row) * 64 + c8);
  }

  float m_run[8], l_run[8];
#pragma unroll
  for (int n = 0; n < 8; ++n) { m_run[n] = -1e30f; l_run[n] = 0.0f; }

  for (int qt = 0; qt < 16; ++qt) {
    __syncthreads();
#pragma unroll
    for (int r = 0; r < 4; ++r) {
      const int ci = t + 256 * r;
      const int row = ci >> 3, c8 = (ci & 7) * 8;
      *reinterpret_cast<u32x4_a*>(&Qs[row][c8]) =
          *reinterpret_cast<const u32x4_a*>(Qh + ((size_t)qt * 128 + row) * 64 + c8);
    }
    __syncthreads();

    f32x4 acc[2][8] = {};
#pragma unroll
    for (int kf = 0; kf < 2; ++kf) {
      u32x4 af[2], bf[8];
#pragma unroll
      for (int i = 0; i < 2; ++i)
        af[i] = *reinterpret_cast<const u32x4_a*>(&Qs[w * 32 + i * 16 + l15][kf * 32 + g * 8]);
#pragma unroll
      for (int n = 0; n < 8; ++n)
        bf[n] = *reinterpret_cast<const u32x4_a*>(&Ks[n * 16 + l15][kf * 32 + g * 8]);
#pragma unroll
      for (int i = 0; i < 2; ++i)
#pragma unroll
        for (int n = 0; n < 8; ++n)
          acc[i][n] = mfma_bf16(af[i], bf[n], acc[i][n]);
    }
    // per-column (s) online max/sum over this tile's 32 q rows (per wave)
#pragma unroll
    for (int n = 0; n < 8; ++n) {
      float mt = -1e30f;
#pragma unroll
      for (int i = 0; i < 2; ++i)
#pragma unroll
        for (int r = 0; r < 4; ++r) mt = fmaxf(mt, acc[i][n][r] * scale);
      mt = fmaxf(mt, __shfl_xor(mt, 16));
      mt = fmaxf(mt, __shfl_xor(mt, 32));
      const float mn = fmaxf(m_run[n], mt);
      float st = 0.0f;
#pragma unroll
      for (int i = 0; i < 2; ++i)
#pragma unroll
        for (int r = 0; r < 4; ++r) st += __expf(acc[i][n][r] * scale - mn);
      st += __shfl_xor(st, 16);
      st += __shfl_xor(st, 32);
      l_run[n] = l_run[n] * __expf(m_run[n] - mn) + st;
      m_run[n] = mn;
    }
  }
  // cross-wave combine
  if (lane < 16) {
#pragma unroll
    for (int n = 0; n < 8; ++n) {
      redM[w][n * 16 + l15] = m_run[n];
      redL[w][n * 16 + l15] = l_run[n];
    }
  }
  __syncthreads();
  if (t < 128) {
    float m = fmaxf(fmaxf(redM[0][t], redM[1][t]), fmaxf(redM[2][t], redM[3][t]));
    float l = 0.0f;
#pragma unroll
    for (int ww = 0; ww < 4; ++ww) l += redL[ww][t] * __expf(redM[ww][t] - m);
    const size_t o = (size_t)bh * 2048 + sblk * 128 + t;
    mG[o] = m;
    invlG[o] = 1.0f / l;
  }
}

// =====================================================================
// Kernel 5: PV pass.  O[q,v] = sum_s exp(S[q,s]-m[s])*invl[s] * V[s,v].
// Block: (qb of 128 q, bh).  Loop s tiles of 128: S=QK^T via MFMA,
// P through LDS (wave-private rows), PV via MFMA with transposed V tile.
// Writes Xh[b*2048+q][h*64+v] bf16.  grid (16, 64).
// =====================================================================
__global__ __launch_bounds__(256) void k_attn(const unsigned short* __restrict__ Q,
                                              const unsigned short* __restrict__ K,
                                              const unsigned short* __restrict__ V,
                                              const float* __restrict__ mG,
                                              const float* __restrict__ invlG,
                                              unsigned short* __restrict__ Xh) {
  __shared__ __align__(16) unsigned short Ks[128][72];
  __shared__ __align__(16) unsigned short Vts[64][136];
  __shared__ __align__(16) unsigned short Ps[128][72];
  const int qb = blockIdx.x, bh = blockIdx.y;
  const int b = bh >> 4, h = bh & 15;
  const unsigned short* Qh = Q + (size_t)bh * 2048 * 64;
  const unsigned short* Kh = K + (size_t)bh * 2048 * 64;
  const unsigned short* Vh = V + (size_t)bh * 2048 * 64;
  const float* mH = mG + (size_t)bh * 2048;
  const float* ilH = invlG + (size_t)bh * 2048;
  const int t = threadIdx.x;
  const int w = t >> 6, lane = t & 63, l15 = lane & 15, g = lane >> 4;
  const float scale = 0.125f;

  // hoist Q fragments (wave-private rows qb*128 + w*32 + i*16 + l15)
  u32x4 aq[2][2];
#pragma unroll
  for (int i = 0; i < 2; ++i)
#pragma unroll
    for (int kf = 0; kf < 2; ++kf)
      aq[i][kf] = *reinterpret_cast<const u32x4_a*>(
          Qh + ((size_t)qb * 128 + w * 32 + i * 16 + l15) * 64 + kf * 32 + g * 8);

  f32x4 oacc[2][4] = {};

  for (int st = 0; st < 16; ++st) {
    const int s0 = st * 128;
    __syncthreads();
#pragma unroll
    for (int r = 0; r < 4; ++r) {
      const int ci = t + 256 * r;
      const int row = ci >> 3, c8 = (ci & 7) * 8;
      *reinterpret_cast<u32x4_a*>(&Ks[row][c8]) =
          *reinterpret_cast<const u32x4_a*>(Kh + ((size_t)s0 + row) * 64 + c8);
      u32x4 vv = *reinterpret_cast<const u32x4_a*>(Vh + ((size_t)s0 + row) * 64 + c8);
      const unsigned short* vp = reinterpret_cast<const unsigned short*>(&vv);
#pragma unroll
      for (int j = 0; j < 8; ++j) Vts[c8 + j][row] = vp[j];
    }
    __syncthreads();

    // S = Q K^T  (rows: this wave's 32 q; cols: 128 s)
    f32x4 sacc[2][8] = {};
#pragma unroll
    for (int kf = 0; kf < 2; ++kf) {
      u32x4 bfr[8];
#pragma unroll
      for (int n = 0; n < 8; ++n)
        bfr[n] = *reinterpret_cast<const u32x4_a*>(&Ks[n * 16 + l15][kf * 32 + g * 8]);
#pragma unroll
      for (int i = 0; i < 2; ++i)
#pragma unroll
        for (int n = 0; n < 8; ++n)
          sacc[i][n] = mfma_bf16(aq[i][kf], bfr[n], sacc[i][n]);
    }

    // two halves of 64 s-columns: P -> LDS (wave-private rows) -> PV MFMA
#pragma unroll
    for (int half = 0; half < 2; ++half) {
#pragma unroll
      for (int n = 0; n < 4; ++n) {
        const int gn = half * 4 + n;
        const int scol = s0 + gn * 16 + l15;
        const float mv = mH[scol];
        const float il = ilH[scol];
#pragma unroll
        for (int i = 0; i < 2; ++i)
#pragma unroll
          for (int r = 0; r < 4; ++r)
            Ps[w * 32 + i * 16 + g * 4 + r][n * 16 + l15] =
                f2bf(__expf(sacc[i][gn][r] * scale - mv) * il);
      }
#pragma unroll
      for (int kf = 0; kf < 2; ++kf) {
        u32x4 pa[2], bv[4];
#pragma unroll
        for (int i = 0; i < 2; ++i)
          pa[i] = *reinterpret_cast<const u32x4_a*>(&Ps[w * 32 + i * 16 + l15][kf * 32 + g * 8]);
#pragma unroll
        for (int n = 0; n < 4; ++n)
          bv[n] = *reinterpret_cast<const u32x4_a*>(
              &Vts[n * 16 + l15][half * 64 + kf * 32 + g * 8]);
#pragma unroll
        for (int i = 0; i < 2; ++i)
#pragma unroll
          for (int n = 0; n < 4; ++n)
            oacc[i][n] = mfma_bf16(pa[i], bv[n], oacc[i][n]);
      }
    }
  }

  // write O to Xh[b*2048+q][h*64+v]
#pragma unroll
  for (int i = 0; i < 2; ++i)
#pragma unroll
    for (int n = 0; n < 4; ++n)
#pragma unroll
      for (int r = 0; r < 4; ++r) {
        const int qrow = qb * 128 + w * 32 + i * 16 + g * 4 + r;
        const int vcol = n * 16 + l15;
        Xh[((size_t)b * 2048 + qrow) * 1024 + h * 64 + vcol] = f2bf(oacc[i][n][r]);
      }
}

// =====================================================================
// Kernel 6: output projection + bias + residual -> d_out fp32.
// A = Xh [8192][1024] bf16, Bt = Wo bf16 [1024][1024]. grid (8, 64).
// =====================================================================
__global__ __launch_bounds__(256) void k_out(const unsigned short* __restrict__ A,
                                             const unsigned short* __restrict__ Bt,
                                             const float* __restrict__ bo,
                                             const float* __restrict__ xres,
                                             float* __restrict__ out) {
  __shared__ __align__(16) unsigned short As[128][72];
  __shared__ __align__(16) unsigned short Bs[128][72];
  const int bn = blockIdx.x, bm = blockIdx.y;
  const int t = threadIdx.x;
  const int w = t >> 6, lane = t & 63, l15 = lane & 15, g = lane >> 4;
  const int wm = w & 1, wn = w >> 1;
  f32x4 acc[4][4] = {};
  const int am0 = bm * 128, bn0 = bn * 128;
  for (int kt = 0; kt < 16; ++kt) {
    const int k0 = kt * 64;
    __syncthreads();
#pragma unroll
    for (int r = 0; r < 4; ++r) {
      const int ci = t + 256 * r;
      const int row = ci >> 3, c8 = (ci & 7) * 8;
      *reinterpret_cast<u32x4_a*>(&As[row][c8]) =
          *reinterpret_cast<const u32x4_a*>(A + (size_t)(am0 + row) * 1024 + k0 + c8);
      *reinterpret_cast<u32x4_a*>(&Bs[row][c8]) =
          *reinterpret_cast<const u32x4_a*>(Bt + (size_t)(bn0 + row) * 1024 + k0 + c8);
    }
    __syncthreads();
#pragma unroll
    for (int kf = 0; kf < 2; ++kf) {
      u32x4 af[4], bf[4];
#pragma unroll
      for (int i = 0; i < 4; ++i)
        af[i] = *reinterpret_cast<const u32x4_a*>(&As[wm * 64 + i * 16 + l15][kf * 32 + g * 8]);
#pragma unroll
      for (int j = 0; j < 4; ++j)
        bf[j] = *reinterpret_cast<const u32x4_a*>(&Bs[wn * 64 + j * 16 + l15][kf * 32 + g * 8]);
#pragma unroll
      for (int i = 0; i < 4; ++i)
#pragma unroll
        for (int j = 0; j < 4; ++j)
          acc[i][j] = mfma_bf16(af[i], bf[j], acc[i][j]);
    }
  }
#pragma unroll
  for (int j = 0; j < 4; ++j) {
    const int col = bn0 + wn * 64 + j * 16 + l15;
    const float bov = bo[col];
#pragma unroll
    for (int i = 0; i < 4; ++i) {
#pragma unroll
      for (int r = 0; r < 4; ++r) {
        const int row = am0 + wm * 64 + i * 16 + g * 4 + r;
        out[(size_t)row * 1024 + col] =
            acc[i][j][r] + bov + xres[(size_t)row * 1024 + col];
      }
    }
  }
}

// =====================================================================
// Launch
// =====================================================================
extern "C" void kernel_launch(void* const* d_in, const int* in_sizes, int n_in,
                              void* d_out, int out_size, void* d_ws, size_t ws_size,
                              hipStream_t stream) {
  const float* x  = (const float*)d_in[0];
  const float* Wq = (const float*)d_in[1];
  const float* bq = (const float*)d_in[2];
  const float* Wk = (const float*)d_in[3];
  const float* bk = (const float*)d_in[4];
  const float* Wv = (const float*)d_in[5];
  const float* bv = (const float*)d_in[6];
  const float* Wo = (const float*)d_in[7];
  const float* bo = (const float*)d_in[8];
  float* out = (float*)d_out;

  // workspace layout (total ~93.3 MB)
  unsigned short* xn  = (unsigned short*)d_ws;          // 8192*1024 bf16
  unsigned short* Wt  = xn + (size_t)8192 * 1024;       // 4096*1024 bf16 (QKV^T rows 0..3071, Wo rows 3072..4095)
  unsigned short* Qb  = Wt + (size_t)4096 * 1024;       // [b][h][2048][64]
  unsigned short* Kb  = Qb + (size_t)8192 * 1024;
  unsigned short* Vb  = Kb + (size_t)8192 * 1024;
  float* mG   = (float*)(Vb + (size_t)8192 * 1024);     // [b*h][2048]
  float* ilG  = mG + 131072;
  unsigned short* XhB = (unsigned short*)(ilG + 131072); // [8192][1024]

  k_ln<<<8192, 256, 0, stream>>>(x, xn);
  k_repw<<<dim3(16, 48), 256, 0, stream>>>(Wq, Wk, Wv, Wt);
  k_repo<<<1024, 256, 0, stream>>>(Wo, Wt + (size_t)3072 * 1024);
  k_qkv<<<dim3(24, 64), 256, 0, stream>>>(xn, Wt, bq, bk, bv, Qb, Kb, Vb);
  k_stats<<<dim3(16, 64), 256, 0, stream>>>(Qb, Kb, mG, ilG);
  k_attn<<<dim3(16, 64), 256, 0, stream>>>(Qb, Kb, Vb, mG, ilG, XhB);
  k_out<<<dim3(8, 64), 256, 0, stream>>>(XhB, Wt + (size_t)3072 * 1024, bo, x, out);
}